// Round 2
// baseline (832.196 us; speedup 1.0000x reference)
//
#include <hip/hip_runtime.h>
#include <hip/hip_bf16.h>
#include <math.h>

typedef __attribute__((ext_vector_type(8))) short bf16x8;
typedef __attribute__((ext_vector_type(4))) float f32x4;
typedef __hip_bfloat16 bf16;

#define MFMA16(a, b, c) __builtin_amdgcn_mfma_f32_16x16x32_bf16((a), (b), (c), 0, 0, 0)

__device__ inline float redmax16(float v) {
    v = fmaxf(v, __shfl_xor(v, 1));
    v = fmaxf(v, __shfl_xor(v, 2));
    v = fmaxf(v, __shfl_xor(v, 4));
    v = fmaxf(v, __shfl_xor(v, 8));
    return v;
}
__device__ inline float redsum16(float v) {
    v += __shfl_xor(v, 1);
    v += __shfl_xor(v, 2);
    v += __shfl_xor(v, 4);
    v += __shfl_xor(v, 8);
    return v;
}

// dst[n*K + k] = bf16(src[k*N + n])  (cast + transpose so GEMM B-operand is K-contiguous)
__global__ void transpose_cast(const float* __restrict__ src, bf16* __restrict__ dst,
                               int K, int N, int total) {
    int i = blockIdx.x * 256 + threadIdx.x;
    if (i >= total) return;
    int n = i / K, k = i - n * K;
    dst[i] = __float2bfloat16(src[(size_t)k * N + n]);
}

union Pack4 { bf16 h[4]; uint2 v; };

// One block per row (1024 f32). rows [0,16384): query -> qn + qraw ; rows [16384,32768): support -> sn
__global__ __launch_bounds__(256) void ln_kernel(
    const float* __restrict__ qf, const float* __restrict__ sf,
    const float* __restrict__ qw, const float* __restrict__ qb,
    const float* __restrict__ sw, const float* __restrict__ sb,
    bf16* __restrict__ qn, bf16* __restrict__ sn, bf16* __restrict__ qraw) {
    int row = blockIdx.x;
    bool isQ = row < 16384;
    int r = isQ ? row : row - 16384;
    const float* src = (isQ ? qf : sf) + (size_t)r * 1024;
    const float* w = isQ ? qw : sw;
    const float* b = isQ ? qb : sb;
    int t = threadIdx.x;
    float4 x = reinterpret_cast<const float4*>(src)[t];
    float s = x.x + x.y + x.z + x.w;
    float ss = x.x * x.x + x.y * x.y + x.z * x.z + x.w * x.w;
    #pragma unroll
    for (int m = 1; m < 64; m <<= 1) { s += __shfl_xor(s, m); ss += __shfl_xor(ss, m); }
    __shared__ float rs_[4], rss_[4];
    int wave = t >> 6;
    if ((t & 63) == 0) { rs_[wave] = s; rss_[wave] = ss; }
    __syncthreads();
    s = rs_[0] + rs_[1] + rs_[2] + rs_[3];
    ss = rss_[0] + rss_[1] + rss_[2] + rss_[3];
    float mu = s * (1.0f / 1024.0f);
    float var = ss * (1.0f / 1024.0f) - mu * mu;
    float rstd = rsqrtf(var + 1e-5f);
    float4 wv = reinterpret_cast<const float4*>(w)[t];
    float4 bv = reinterpret_cast<const float4*>(b)[t];
    Pack4 o;
    o.h[0] = __float2bfloat16((x.x - mu) * rstd * wv.x + bv.x);
    o.h[1] = __float2bfloat16((x.y - mu) * rstd * wv.y + bv.y);
    o.h[2] = __float2bfloat16((x.z - mu) * rstd * wv.z + bv.z);
    o.h[3] = __float2bfloat16((x.w - mu) * rstd * wv.w + bv.w);
    bf16* dst = (isQ ? qn : sn) + (size_t)r * 1024 + t * 4;
    *reinterpret_cast<uint2*>(dst) = o.v;
    if (isQ) {
        Pack4 o2;
        o2.h[0] = __float2bfloat16(x.x);
        o2.h[1] = __float2bfloat16(x.y);
        o2.h[2] = __float2bfloat16(x.z);
        o2.h[3] = __float2bfloat16(x.w);
        bf16* d2 = qraw + (size_t)r * 1024 + t * 4;
        *reinterpret_cast<uint2*>(d2) = o2.v;
    }
}

// C = A(MxK) @ Bt(NxK)^T, both bf16 with K contiguous. 128x128 tile, BK=64, 4 waves of 64x64.
// MODE 0: out bf16, per-head layout [b][h][n][d]   (Q, K projections)
// MODE 1: out bf16, per-head transposed [b][h][d][n] (V projection)
// MODE 2: out bf16 = sigmoid(acc + bias), plain [M][N]  (gate)
// MODE 3: out f32 = resid + gate * (acc + bias), plain [M][N]  (final)
template <int MODE>
__global__ __launch_bounds__(256) void gemm_bf16(
    const bf16* __restrict__ A, const bf16* __restrict__ Bt,
    const float* __restrict__ bias, void* __restrict__ outp,
    const bf16* __restrict__ gate, const float* __restrict__ resid,
    int M, int N, int Kd) {
    __shared__ short lsA[128 * 72];  // pad 64 -> 72 elems: row stride 144B, 2-way conflict only
    __shared__ short lsB[128 * 72];
    int tid = threadIdx.x;
    int m0 = blockIdx.x * 128, n0 = blockIdx.y * 128;
    int wave = tid >> 6, lane = tid & 63;
    int wr = wave >> 1, wc = wave & 1;
    int lrow = lane & 15, kgrp = lane >> 4;
    f32x4 acc[4][4];
    #pragma unroll
    for (int i = 0; i < 4; i++)
        #pragma unroll
        for (int j = 0; j < 4; j++) acc[i][j] = (f32x4){0.f, 0.f, 0.f, 0.f};
    int nkt = Kd >> 6;
    for (int kt = 0; kt < nkt; kt++) {
        int k0 = kt * 64;
        #pragma unroll
        for (int i = 0; i < 4; i++) {
            int ci = tid + i * 256;     // 1024 16B-chunks per operand tile
            int row = ci >> 3, cc = ci & 7;
            *reinterpret_cast<bf16x8*>(lsA + row * 72 + cc * 8) =
                *reinterpret_cast<const bf16x8*>(A + (size_t)(m0 + row) * Kd + k0 + cc * 8);
            *reinterpret_cast<bf16x8*>(lsB + row * 72 + cc * 8) =
                *reinterpret_cast<const bf16x8*>(Bt + (size_t)(n0 + row) * Kd + k0 + cc * 8);
        }
        __syncthreads();
        #pragma unroll
        for (int kc = 0; kc < 2; kc++) {
            bf16x8 aF[4], bF[4];
            #pragma unroll
            for (int mf = 0; mf < 4; mf++)
                aF[mf] = *reinterpret_cast<const bf16x8*>(
                    lsA + (wr * 64 + mf * 16 + lrow) * 72 + kc * 32 + kgrp * 8);
            #pragma unroll
            for (int nf = 0; nf < 4; nf++)
                bF[nf] = *reinterpret_cast<const bf16x8*>(
                    lsB + (wc * 64 + nf * 16 + lrow) * 72 + kc * 32 + kgrp * 8);
            #pragma unroll
            for (int mf = 0; mf < 4; mf++)
                #pragma unroll
                for (int nf = 0; nf < 4; nf++)
                    acc[mf][nf] = MFMA16(aF[mf], bF[nf], acc[mf][nf]);
        }
        __syncthreads();
    }
    #pragma unroll
    for (int mf = 0; mf < 4; mf++) {
        #pragma unroll
        for (int nf = 0; nf < 4; nf++) {
            #pragma unroll
            for (int r = 0; r < 4; r++) {
                int gM = m0 + wr * 64 + mf * 16 + kgrp * 4 + r;
                int gN = n0 + wc * 64 + nf * 16 + lrow;
                float v = acc[mf][nf][r] + bias[gN];
                if (MODE == 0) {
                    int b = gM >> 10, n = gM & 1023, h = gN >> 6, d = gN & 63;
                    ((bf16*)outp)[(((size_t)(b * 4 + h)) << 16) + (n << 6) + d] = __float2bfloat16(v);
                } else if (MODE == 1) {
                    int b = gM >> 10, n = gM & 1023, h = gN >> 6, d = gN & 63;
                    ((bf16*)outp)[(((size_t)(b * 4 + h)) << 16) + (d << 10) + n] = __float2bfloat16(v);
                } else if (MODE == 2) {
                    float g = 1.0f / (1.0f + __expf(-v));
                    ((bf16*)outp)[(size_t)gM * N + gN] = __float2bfloat16(g);
                } else {
                    float g = __bfloat162float(gate[(size_t)gM * N + gN]);
                    float q = resid[(size_t)gM * N + gN];
                    ((float*)outp)[(size_t)gM * N + gN] = q + g * v;
                }
            }
        }
    }
}

// Fused attention per (b,h): 2-pass online softmax (recompute QK^T), writes f32 attn + bf16 ctx.
// grid = 64 heads * 16 q-tiles; block = 4 waves, each wave owns 16 q rows.
__global__ __launch_bounds__(256) void attn_kernel(
    const bf16* __restrict__ Qh, const bf16* __restrict__ Kh, const bf16* __restrict__ Vt,
    const float* __restrict__ mask, float* __restrict__ attn_out, bf16* __restrict__ ctx) {
    __shared__ bf16 Plds[4 * 16 * 32];  // per-wave 16x32 P tile (stride 32 elems: 2-way, free)
    int bh = blockIdx.x >> 4, qt = blockIdx.x & 15;
    int b = bh >> 2, h = bh & 3;
    int wave = threadIdx.x >> 6, lane = threadIdx.x & 63;
    int lrow = lane & 15, kgrp = lane >> 4;
    const bf16* Qb = Qh + ((size_t)bh << 16);
    const bf16* Kb = Kh + ((size_t)bh << 16);
    const bf16* Vb = Vt + ((size_t)bh << 16);
    const float* mb = mask + b * 1024;
    int q0 = qt * 64 + wave * 16;
    bf16x8 aQ0 = *reinterpret_cast<const bf16x8*>(Qb + (q0 + lrow) * 64 + kgrp * 8);
    bf16x8 aQ1 = *reinterpret_cast<const bf16x8*>(Qb + (q0 + lrow) * 64 + 32 + kgrp * 8);
    float mrun[4], ssum[4];
    #pragma unroll
    for (int r = 0; r < 4; r++) { mrun[r] = -1e30f; ssum[r] = 0.f; }
    // pass 1: row max + sum of exp
    for (int kt = 0; kt < 64; kt++) {
        bf16x8 bK0 = *reinterpret_cast<const bf16x8*>(Kb + (kt * 16 + lrow) * 64 + kgrp * 8);
        bf16x8 bK1 = *reinterpret_cast<const bf16x8*>(Kb + (kt * 16 + lrow) * 64 + 32 + kgrp * 8);
        f32x4 acc = (f32x4){0.f, 0.f, 0.f, 0.f};
        acc = MFMA16(aQ0, bK0, acc);
        acc = MFMA16(aQ1, bK1, acc);
        float mv = 5.0f * mb[kt * 16 + lrow];
        #pragma unroll
        for (int r = 0; r < 4; r++) {
            float s = acc[r] * 0.125f + mv;
            float tm = redmax16(s);
            float nm = fmaxf(mrun[r], tm);
            float e = __expf(s - nm);
            float es = redsum16(e);
            ssum[r] = ssum[r] * __expf(mrun[r] - nm) + es;
            mrun[r] = nm;
        }
    }
    float inv[4];
    #pragma unroll
    for (int r = 0; r < 4; r++) inv[r] = 1.0f / ssum[r];
    f32x4 cacc[4];
    #pragma unroll
    for (int nf = 0; nf < 4; nf++) cacc[nf] = (f32x4){0.f, 0.f, 0.f, 0.f};
    float* aout = attn_out + ((size_t)bh << 20) + (size_t)q0 * 1024;
    // pass 2: recompute, write normalized attn, accumulate P@V
    for (int kt = 0; kt < 64; kt++) {
        bf16x8 bK0 = *reinterpret_cast<const bf16x8*>(Kb + (kt * 16 + lrow) * 64 + kgrp * 8);
        bf16x8 bK1 = *reinterpret_cast<const bf16x8*>(Kb + (kt * 16 + lrow) * 64 + 32 + kgrp * 8);
        f32x4 acc = (f32x4){0.f, 0.f, 0.f, 0.f};
        acc = MFMA16(aQ0, bK0, acc);
        acc = MFMA16(aQ1, bK1, acc);
        float mv = 5.0f * mb[kt * 16 + lrow];
        #pragma unroll
        for (int r = 0; r < 4; r++) {
            float s = acc[r] * 0.125f + mv;
            float p = __expf(s - mrun[r]) * inv[r];
            aout[(kgrp * 4 + r) * 1024 + kt * 16 + lrow] = p;
            Plds[wave * 512 + (kgrp * 4 + r) * 32 + ((kt & 1) << 4) + lrow] = __float2bfloat16(p);
        }
        if (kt & 1) {
            __syncthreads();  // make the wave's cross-lane P writes visible
            bf16x8 aP = *reinterpret_cast<const bf16x8*>(&Plds[wave * 512 + lrow * 32 + kgrp * 8]);
            int k2 = (kt >> 1) * 32;
            #pragma unroll
            for (int nf = 0; nf < 4; nf++) {
                bf16x8 bV = *reinterpret_cast<const bf16x8*>(Vb + (nf * 16 + lrow) * 1024 + k2 + kgrp * 8);
                cacc[nf] = MFMA16(aP, bV, cacc[nf]);
            }
            __syncthreads();
        }
    }
    #pragma unroll
    for (int nf = 0; nf < 4; nf++) {
        #pragma unroll
        for (int r = 0; r < 4; r++) {
            int qrow = q0 + kgrp * 4 + r;
            ctx[((size_t)(b * 1024 + qrow)) * 256 + h * 64 + nf * 16 + lrow] =
                __float2bfloat16(cacc[nf][r]);
        }
    }
}

extern "C" void kernel_launch(void* const* d_in, const int* in_sizes, int n_in,
                              void* d_out, int out_size, void* d_ws, size_t ws_size,
                              hipStream_t stream) {
    const float* qf = (const float*)d_in[0];
    const float* sf = (const float*)d_in[1];
    const float* mask = (const float*)d_in[2];
    const float* lnqw = (const float*)d_in[3];
    const float* lnqb = (const float*)d_in[4];
    const float* lnsw = (const float*)d_in[5];
    const float* lnsb = (const float*)d_in[6];
    const float* Wq = (const float*)d_in[7];
    const float* bq = (const float*)d_in[8];
    const float* Wk = (const float*)d_in[9];
    const float* bk = (const float*)d_in[10];
    const float* Wv = (const float*)d_in[11];
    const float* bv = (const float*)d_in[12];
    const float* Wo = (const float*)d_in[13];
    const float* bo = (const float*)d_in[14];
    const float* Wg = (const float*)d_in[15];
    const float* bg = (const float*)d_in[16];

    char* ws = (char*)d_ws;
    const size_t MB = 1024 * 1024;
    bf16* wqt  = (bf16*)(ws + 0);                 // 256x1024  (0.5 MB)
    bf16* wkt  = (bf16*)(ws + 512 * 1024);        // 256x1024
    bf16* wvt  = (bf16*)(ws + 1024 * 1024);       // 256x1024
    bf16* wot  = (bf16*)(ws + 1536 * 1024);       // 1024x256
    bf16* wgt  = (bf16*)(ws + 2 * MB);            // 1024x1024 (2 MB)
    bf16* qn   = (bf16*)(ws + 4 * MB);            // 16384x1024 (32 MB); later aliased by gate
    bf16* sn   = (bf16*)(ws + 36 * MB);           // 16384x1024 (32 MB); later aliased by ctx
    bf16* qraw = (bf16*)(ws + 68 * MB);           // 16384x1024 (32 MB)
    bf16* Qh   = (bf16*)(ws + 100 * MB);          // [64][1024][64] (8 MB)
    bf16* Kh   = (bf16*)(ws + 108 * MB);          // [64][1024][64]
    bf16* Vt   = (bf16*)(ws + 116 * MB);          // [64][64][1024]
    bf16* gate = qn;   // qn dead after Q projection
    bf16* ctx  = sn;   // sn dead after K,V projections

    float* enh = (float*)d_out;
    float* attn = enh + (size_t)16 * 1024 * 1024;

    // 1. weight transpose + bf16 cast
    transpose_cast<<<1024, 256, 0, stream>>>(Wq, wqt, 1024, 256, 262144);
    transpose_cast<<<1024, 256, 0, stream>>>(Wk, wkt, 1024, 256, 262144);
    transpose_cast<<<1024, 256, 0, stream>>>(Wv, wvt, 1024, 256, 262144);
    transpose_cast<<<1024, 256, 0, stream>>>(Wo, wot, 256, 1024, 262144);
    transpose_cast<<<4096, 256, 0, stream>>>(Wg, wgt, 1024, 1024, 1048576);
    // 2. layernorm + casts
    ln_kernel<<<32768, 256, 0, stream>>>(qf, sf, lnqw, lnqb, lnsw, lnsb, qn, sn, qraw);
    // 3. projections
    gemm_bf16<0><<<dim3(128, 2), 256, 0, stream>>>(qn, wqt, bq, Qh, nullptr, nullptr, 16384, 256, 1024);
    gemm_bf16<0><<<dim3(128, 2), 256, 0, stream>>>(sn, wkt, bk, Kh, nullptr, nullptr, 16384, 256, 1024);
    gemm_bf16<1><<<dim3(128, 2), 256, 0, stream>>>(sn, wvt, bv, Vt, nullptr, nullptr, 16384, 256, 1024);
    // 4. attention (writes attn f32 + ctx bf16)
    attn_kernel<<<1024, 256, 0, stream>>>(Qh, Kh, Vt, mask, attn, ctx);
    // 5. gate = sigmoid(qraw @ Wg + bg)
    gemm_bf16<2><<<dim3(128, 8), 256, 0, stream>>>(qraw, wgt, bg, gate, nullptr, nullptr, 16384, 1024, 1024);
    // 6. enhanced = qf + gate * (ctx @ Wo + bo)
    gemm_bf16<3><<<dim3(128, 8), 256, 0, stream>>>(ctx, wot, bo, enh, gate, qf, 16384, 1024, 256);
}